// Round 3
// baseline (120.033 us; speedup 1.0000x reference)
//
#include <hip/hip_runtime.h>
#include <hip/hip_bf16.h>

#define F 64
#define R 64
#define O 64
#define BLOCK_B 64   // batch rows per block (512 threads, 8 waves)

typedef short bf16x8 __attribute__((ext_vector_type(8)));
typedef float f32x4 __attribute__((ext_vector_type(4)));
typedef float f32x2 __attribute__((ext_vector_type(2)));

static __device__ __forceinline__ short f2bf(float f) {
    unsigned u = __builtin_bit_cast(unsigned, f);
    unsigned r = (u + 0x7fffu + ((u >> 16) & 1u)) >> 16;
    return (short)r;
}

// pack two f32 -> two bf16 (truncation) in one v_perm_b32
static __device__ __forceinline__ unsigned pack2bf_trunc(float lo, float hi) {
    return __builtin_amdgcn_perm(__builtin_bit_cast(unsigned, hi),
                                 __builtin_bit_cast(unsigned, lo), 0x07060302u);
}

// build one A-fragment (8 bf16): elements j = wn[j-pair] * x, truncated to bf16
static __device__ __forceinline__ bf16x8 mk_frag(const f32x2* wn, float x) {
    union { bf16x8 v; unsigned u[4]; } r;
#pragma unroll
    for (int i = 0; i < 4; ++i) {
        f32x2 p = wn[i] * x;
        r.u[i] = pack2bf_trunc(p.x, p.y);
    }
    return r.v;
}

// ---------------------------------------------------------------------------
// Prep kernel (flat, 146 blocks x 256):
//   threads [0, 33280): pack W (fp32) -> Wpk (bf16, MFMA B-fragment order),
//     nt-major so one wave's f-stream is contiguous:
//     dst = ((nt*65 + f)*2 + kk)*64 + lane   (bf16x8 units)
//     value = W[o*4160 + f*64 + r], o = nt*16+(lane&15), r = (lane>>4)*8+j+kk*32
//   threads [33280, 37376): prm[u] = {s, mn*s, t, c}, u = f*64 + r
// ---------------------------------------------------------------------------
__global__ __launch_bounds__(256) void fq_prep(
        const float* __restrict__ tt, const float* __restrict__ mean,
        const float* __restrict__ std_, const float* __restrict__ W,
        float* __restrict__ prm, unsigned short* __restrict__ Wpk)
{
    const int tg = blockIdx.x * 256 + threadIdx.x;
    if (tg < 65 * 512) {
        const int f    = tg >> 9;
        const int u8   = tg & 511;
        const int lane = u8 & 63;
        const int kk   = (u8 >> 6) & 1;
        const int nt   = u8 >> 7;
        const int o    = nt * 16 + (lane & 15);
        const int rb   = ((lane >> 4) << 3) + kk * 32;
        const float* src = W + o * 4160 + f * 64 + rb;
        unsigned short v[8];
#pragma unroll
        for (int j = 0; j < 8; ++j) v[j] = (unsigned short)f2bf(src[j]);
        const int dst = ((nt * 65 + f) * 2 + kk) * 64 + lane;
        *(bf16x8*)(Wpk + (size_t)dst * 8) = *(bf16x8*)v;
    } else if (tg < 65 * 512 + 4096) {
        const int u = tg - 65 * 512;
        float sd = std_[u];
        float mn = mean[u];
        float th = tanhf(tt[u]);
        float s  = 1.2011224087864498f / sd;  // sqrt(log2(e)) / std
        float4 p;
        p.x = s;
        p.y = mn * s;
        p.z = th;
        p.w = 0.5f * (1.0f - th);
        ((float4*)prm)[u] = p;
    }
}

// ---------------------------------------------------------------------------
// Main fused kernel: block = 64 batch rows, 512 threads (8 waves).
// Stage 1: wave w computes fire for rows 8w..8w+7 (lane = rule r), float2-packed.
// Stage 2: wave w -> nt = w>>1, g = w&1: tile rows [32g,32g+32) x cols
//          [16nt,16nt+16). A-operand = bf16(x_f * wn) built per f; the two
//          waves of an nt-pair load identical Wp addresses (L1 sharing).
// ---------------------------------------------------------------------------
__global__ __launch_bounds__(512, 4) void fq_main(
        const float* __restrict__ X,
        const float4* __restrict__ prm,
        const bf16x8* __restrict__ Wp,
        float* __restrict__ out)
{
    __shared__ __align__(16) float fire_lds[BLOCK_B][R + 4];  // pad 68
    __shared__ float rinv[BLOCK_B];

    const int t    = threadIdx.x;
    const int lane = t & 63;
    const int w    = __builtin_amdgcn_readfirstlane(t >> 6);  // wave id 0..7
    const int b0   = blockIdx.x * BLOCK_B;

    // ---- stage 1: firing strengths, rows 8w..8w+7, lane = r ----------------
    f32x2 fire2[4];
#pragma unroll
    for (int i = 0; i < 4; ++i) fire2[i] = (f32x2){1.f, 1.f};

    const float* Xb = X + (size_t)(b0 + 8 * w) * 64;
    for (int f = 0; f < F; ++f) {
        float4 p = prm[f * 64 + lane];    // {s, mn*s, t, c}
        f32x2 t2 = (f32x2){p.z, p.z};
        f32x2 c2 = (f32x2){p.w, p.w};
#pragma unroll
        for (int i = 0; i < 4; ++i) {
            float x0 = Xb[(2 * i) * 64 + f];      // uniform -> s_load
            float x1 = Xb[(2 * i + 1) * 64 + f];
            f32x2 z;
            z.x = __builtin_fmaf(x0, p.x, -p.y);
            z.y = __builtin_fmaf(x1, p.x, -p.y);
            f32x2 nz = -(z * z);
            f32x2 g;
            g.x = __builtin_amdgcn_exp2f(nz.x);
            g.y = __builtin_amdgcn_exp2f(nz.y);
            fire2[i] *= g * t2 + c2;
        }
    }
#pragma unroll
    for (int i = 0; i < 4; ++i) {
        fire_lds[8 * w + 2 * i][lane]     = fire2[i].x;
        fire_lds[8 * w + 2 * i + 1][lane] = fire2[i].y;
    }
    __syncthreads();

    // ---- row sums: 8 threads per row, shuffle-reduce ------------------------
    {
        const int row = t >> 3;
        const int c8  = (t & 7) * 8;
        f32x4 s0 = *(const f32x4*)&fire_lds[row][c8];
        f32x4 s1 = *(const f32x4*)&fire_lds[row][c8 + 4];
        float s = (s0[0] + s0[1]) + (s0[2] + s0[3]) +
                  (s1[0] + s1[1]) + (s1[2] + s1[3]);
        s += __shfl_xor(s, 1);
        s += __shfl_xor(s, 2);
        s += __shfl_xor(s, 4);
        if ((t & 7) == 0) rinv[row] = 1.0f / s;
    }
    __syncthreads();

    // ---- stage 2 ------------------------------------------------------------
    const int m_in = lane & 15;
    const int quad = lane >> 4;
    const int nt   = w >> 1;
    const int g    = w & 1;
    const int ra   = 32 * g + m_in;        // A-frag row (frag a)
    const int rb   = ra + 16;              // frag b
    const float rs_a = rinv[ra];
    const float rs_b = rinv[rb];
    const int q8 = quad * 8;

    // normalized w fragments, fp32, register-resident: wn[kk*4+i] = {k=2i, k=2i+1}
    f32x2 wna[8], wnb[8];
#pragma unroll
    for (int kk = 0; kk < 2; ++kk) {
        f32x4 a0 = *(const f32x4*)&fire_lds[ra][q8 + 32 * kk];
        f32x4 a1 = *(const f32x4*)&fire_lds[ra][q8 + 32 * kk + 4];
        f32x4 b0 = *(const f32x4*)&fire_lds[rb][q8 + 32 * kk];
        f32x4 b1 = *(const f32x4*)&fire_lds[rb][q8 + 32 * kk + 4];
        wna[kk * 4 + 0] = (f32x2){a0[0], a0[1]} * rs_a;
        wna[kk * 4 + 1] = (f32x2){a0[2], a0[3]} * rs_a;
        wna[kk * 4 + 2] = (f32x2){a1[0], a1[1]} * rs_a;
        wna[kk * 4 + 3] = (f32x2){a1[2], a1[3]} * rs_a;
        wnb[kk * 4 + 0] = (f32x2){b0[0], b0[1]} * rs_b;
        wnb[kk * 4 + 1] = (f32x2){b0[2], b0[3]} * rs_b;
        wnb[kk * 4 + 2] = (f32x2){b1[0], b1[1]} * rs_b;
        wnb[kk * 4 + 3] = (f32x2){b1[2], b1[3]} * rs_b;
    }

    const bf16x8* wpb = Wp + (size_t)(nt * 130) * 64 + lane;
    const float* Xa_p = X + (size_t)(b0 + ra) * 64;
    const float* Xb_p = X + (size_t)(b0 + rb) * 64;

    f32x4 acc_a = (f32x4){0.f, 0.f, 0.f, 0.f};
    f32x4 acc_b = (f32x4){0.f, 0.f, 0.f, 0.f};

    for (int f4 = 0; f4 < 16; ++f4) {
        f32x4 xa4 = *(const f32x4*)(Xa_p + 4 * f4);
        f32x4 xb4 = *(const f32x4*)(Xb_p + 4 * f4);
#pragma unroll
        for (int j = 0; j < 4; ++j) {
            const int f = f4 * 4 + j;
            bf16x8 bb0 = wpb[(2 * f) * 64];
            bf16x8 bb1 = wpb[(2 * f + 1) * 64];
            bf16x8 fa0 = mk_frag(wna + 0, xa4[j]);
            bf16x8 fa1 = mk_frag(wna + 4, xa4[j]);
            bf16x8 fb0 = mk_frag(wnb + 0, xb4[j]);
            bf16x8 fb1 = mk_frag(wnb + 4, xb4[j]);
            acc_a = __builtin_amdgcn_mfma_f32_16x16x32_bf16(fa0, bb0, acc_a, 0, 0, 0);
            acc_a = __builtin_amdgcn_mfma_f32_16x16x32_bf16(fa1, bb1, acc_a, 0, 0, 0);
            acc_b = __builtin_amdgcn_mfma_f32_16x16x32_bf16(fb0, bb0, acc_b, 0, 0, 0);
            acc_b = __builtin_amdgcn_mfma_f32_16x16x32_bf16(fb1, bb1, acc_b, 0, 0, 0);
        }
    }

    // bias column (Xa[:,64] = 1): a = bf16(wn)
    {
        bf16x8 bb0 = wpb[128 * 64];
        bf16x8 bb1 = wpb[129 * 64];
        bf16x8 fa0 = mk_frag(wna + 0, 1.0f);
        bf16x8 fa1 = mk_frag(wna + 4, 1.0f);
        bf16x8 fb0 = mk_frag(wnb + 0, 1.0f);
        bf16x8 fb1 = mk_frag(wnb + 4, 1.0f);
        acc_a = __builtin_amdgcn_mfma_f32_16x16x32_bf16(fa0, bb0, acc_a, 0, 0, 0);
        acc_a = __builtin_amdgcn_mfma_f32_16x16x32_bf16(fa1, bb1, acc_a, 0, 0, 0);
        acc_b = __builtin_amdgcn_mfma_f32_16x16x32_bf16(fb0, bb0, acc_b, 0, 0, 0);
        acc_b = __builtin_amdgcn_mfma_f32_16x16x32_bf16(fb1, bb1, acc_b, 0, 0, 0);
    }

    // epilogue: C/D layout col = lane&15, row = quad*4 + reg
#pragma unroll
    for (int reg = 0; reg < 4; ++reg) {
        const int col = nt * 16 + m_in;
        out[(size_t)(b0 + 32 * g + quad * 4 + reg) * 64 + col]      = acc_a[reg];
        out[(size_t)(b0 + 32 * g + 16 + quad * 4 + reg) * 64 + col] = acc_b[reg];
    }
}

extern "C" void kernel_launch(void* const* d_in, const int* in_sizes, int n_in,
                              void* d_out, int out_size, void* d_ws, size_t ws_size,
                              hipStream_t stream) {
    const float* X    = (const float*)d_in[0];
    const float* tt   = (const float*)d_in[1];
    const float* mean = (const float*)d_in[2];
    const float* std_ = (const float*)d_in[3];
    const float* W    = (const float*)d_in[4];
    float* out = (float*)d_out;

    // workspace: prm (float4 x 4096 = 64 KiB) | Wpk (bf16 x 65*512*8 = 520 KiB)
    float* prm = (float*)d_ws;
    unsigned short* Wpk = (unsigned short*)((char*)d_ws + 65536);

    fq_prep<<<146, 256, 0, stream>>>(tt, mean, std_, W, prm, Wpk);

    const int nblocks = 32768 / BLOCK_B;  // 512
    fq_main<<<nblocks, 512, 0, stream>>>(X, (const float4*)prm,
                                         (const bf16x8*)Wpk, out);
}